// Round 2
// baseline (5167.946 us; speedup 1.0000x reference)
//
#include <hip/hip_runtime.h>
#include <hip/hip_bf16.h>
#include <cstddef>

// ---------------------------------------------------------------------------
// Mamba S6 layer. B=4, S=2048, D_MODEL=1024, D_STATE=16, D_CONV=3,
// D_INNER=2048, M=B*S=8192.
// Round 2: fp32 GEMM compute, bf16 storage for large intermediates.
// Workspace budget: 161 MiB (round-1 crash hypothesis: 257 MiB > ws_size).
// ---------------------------------------------------------------------------

#define TILE_M 64
#define TILE_N 64
#define TILE_K 16

typedef __hip_bfloat16 bf16;

template <typename T>
__device__ __forceinline__ float to_f(T v);
template <> __device__ __forceinline__ float to_f<float>(float v) { return v; }
template <> __device__ __forceinline__ float to_f<bf16>(bf16 v) { return __bfloat162float(v); }

// C[M,N] = A[M,K] @ W[K,N]; mode 1: softplus(x + bias[n]) epilogue.
template <typename TA, typename TC>
__global__ __launch_bounds__(256) void gemm_t(
    const TA* __restrict__ A, const float* __restrict__ W,
    TC* __restrict__ C, int M, int N, int K,
    int lda, int ldw, int ldc,
    const float* __restrict__ bias, int mode)
{
    __shared__ float As[TILE_K][TILE_M + 4];
    __shared__ float Ws[TILE_K][TILE_N + 4];

    const int tid = threadIdx.x;
    const int tx = tid & 15;
    const int ty = tid >> 4;
    const int row0 = blockIdx.y * TILE_M;
    const int col0 = blockIdx.x * TILE_N;

    const int a_k = tid & 15;
    const int a_r = tid >> 4;
    const int w_c = tid & 63;
    const int w_k = tid >> 6;

    float acc[4][4] = {};

    for (int k0 = 0; k0 < K; k0 += TILE_K) {
        #pragma unroll
        for (int i = 0; i < 4; ++i) {
            int r  = a_r + 16 * i;
            int gr = row0 + r;
            int gk = k0 + a_k;
            As[a_k][r] = (gr < M && gk < K) ? to_f(A[(size_t)gr * lda + gk]) : 0.f;
        }
        #pragma unroll
        for (int i = 0; i < 4; ++i) {
            int kk = w_k + 4 * i;
            int gk = k0 + kk;
            int gc = col0 + w_c;
            Ws[kk][w_c] = (gk < K && gc < N) ? W[(size_t)gk * ldw + gc] : 0.f;
        }
        __syncthreads();
        #pragma unroll
        for (int kk = 0; kk < TILE_K; ++kk) {
            float4 av = *(const float4*)&As[kk][ty * 4];
            float4 wv = *(const float4*)&Ws[kk][tx * 4];
            float ar[4] = {av.x, av.y, av.z, av.w};
            float wr[4] = {wv.x, wv.y, wv.z, wv.w};
            #pragma unroll
            for (int i = 0; i < 4; ++i)
                #pragma unroll
                for (int j = 0; j < 4; ++j)
                    acc[i][j] = fmaf(ar[i], wr[j], acc[i][j]);
        }
        __syncthreads();
    }

    #pragma unroll
    for (int i = 0; i < 4; ++i) {
        int gr = row0 + ty * 4 + i;
        if (gr >= M) continue;
        int gc0 = col0 + tx * 4;
        float v[4];
        #pragma unroll
        for (int j = 0; j < 4; ++j) {
            float t = acc[i][j];
            if (mode == 1) {
                int gc = gc0 + j;
                t += bias[gc < N ? gc : 0];
                t = fmaxf(t, 0.f) + log1pf(__expf(-fabsf(t)));  // stable softplus
            }
            v[j] = t;
        }
        TC* dst = C + (size_t)gr * ldc + gc0;
        if constexpr (__hip_internal::is_same<TC, float>::value) {
            if (gc0 + 3 < N) {
                *(float4*)dst = make_float4(v[0], v[1], v[2], v[3]);
            } else {
                #pragma unroll
                for (int j = 0; j < 4; ++j)
                    if (gc0 + j < N) dst[j] = v[j];
            }
        } else {
            if (gc0 + 3 < N) {
                alignas(8) bf16 h[4];
                #pragma unroll
                for (int j = 0; j < 4; ++j) h[j] = __float2bfloat16(v[j]);
                *(ushort4*)dst = *(ushort4*)h;
            } else {
                #pragma unroll
                for (int j = 0; j < 4; ++j)
                    if (gc0 + j < N) dst[j] = __float2bfloat16(v[j]);
            }
        }
    }
}

// Depthwise conv (width 3, SAME, per-sequence) + bias + SiLU.
// u_raw: comb[:, 0:2048] bf16, row stride 4096. Output uc[8192,2048] bf16.
__global__ __launch_bounds__(256) void conv_silu_kernel(
    const bf16* __restrict__ comb,
    const float* __restrict__ conv_w, const float* __restrict__ conv_b,
    bf16* __restrict__ uc)
{
    int idx = blockIdx.x * 256 + threadIdx.x;
    int d = idx & 2047;
    int m = idx >> 11;
    int s = m & 2047;

    float w0 = conv_w[d * 3 + 0];
    float w1 = conv_w[d * 3 + 1];
    float w2 = conv_w[d * 3 + 2];

    float acc = conv_b[d];
    if (s > 0)    acc = fmaf(__bfloat162float(comb[(size_t)(m - 1) * 4096 + d]), w0, acc);
    acc = fmaf(__bfloat162float(comb[(size_t)m * 4096 + d]), w1, acc);
    if (s < 2047) acc = fmaf(__bfloat162float(comb[(size_t)(m + 1) * 4096 + d]), w2, acc);

    float sig = 1.f / (1.f + __expf(-acc));
    uc[(size_t)m * 2048 + d] = __float2bfloat16(acc * sig);
}

// Selective scan over s, one thread per (b,d). Fuses +u*D and *silu(x_gate).
// Reads delta fp32 [8192,2048], writes gated y over it in-place.
__global__ __launch_bounds__(64) void scan_kernel(
    const float* __restrict__ bc,     // [8192,32]: B cols 0..15, C cols 16..31
    const bf16* __restrict__ uc,      // [8192,2048]
    const bf16* __restrict__ comb,    // x_gate at [:, 2048:], stride 4096
    float* __restrict__ delta,        // [8192,2048], in-place -> y2
    const float* __restrict__ A_log,  // [2048,16]
    const float* __restrict__ D_param)// [2048]
{
    int lane = threadIdx.x;
    int blk = blockIdx.x;
    int b = blk >> 5;
    int d = ((blk & 31) << 6) + lane;

    float a[16];
    #pragma unroll
    for (int n = 0; n < 16; ++n) a[n] = -__expf(A_log[d * 16 + n]);
    float Dp = D_param[d];

    float h[16];
    #pragma unroll
    for (int n = 0; n < 16; ++n) h[n] = 0.f;

    for (int s = 0; s < 2048; ++s) {
        size_t m = (size_t)b * 2048 + s;
        float dv  = delta[m * 2048 + d];
        float uv  = __bfloat162float(uc[m * 2048 + d]);
        float xgv = __bfloat162float(comb[m * 4096 + 2048 + d]);

        const float4* bc4 = (const float4*)(bc + m * 32);
        float4 Bq[4], Cq[4];
        #pragma unroll
        for (int q = 0; q < 4; ++q) Bq[q] = bc4[q];
        #pragma unroll
        for (int q = 0; q < 4; ++q) Cq[q] = bc4[4 + q];
        const float* Bv = (const float*)Bq;
        const float* Cv = (const float*)Cq;

        float y = 0.f;
        #pragma unroll
        for (int n = 0; n < 16; ++n) {
            h[n] = __expf(dv * a[n]) * h[n] + (dv * Bv[n]) * uv;
            y = fmaf(h[n], Cv[n], y);
        }

        float sig = 1.f / (1.f + __expf(-xgv));
        float y2 = (y + uv * Dp) * (xgv * sig);
        delta[m * 2048 + d] = y2;
    }
}

extern "C" void kernel_launch(void* const* d_in, const int* in_sizes, int n_in,
                              void* d_out, int out_size, void* d_ws, size_t ws_size,
                              hipStream_t stream) {
    const float* x    = (const float*)d_in[0];
    const float* w1   = (const float*)d_in[1];   // [1024,4096]
    const float* cw   = (const float*)d_in[2];   // [2048,1,3]
    const float* cb   = (const float*)d_in[3];   // [2048]
    const float* w2   = (const float*)d_in[4];   // [2048,2080]
    const float* w3   = (const float*)d_in[5];   // [2048,2048]
    const float* dtb  = (const float*)d_in[6];   // [2048]
    const float* w4   = (const float*)d_in[7];   // [2048,1024]
    const float* alog = (const float*)d_in[8];   // [2048,16]
    const float* dpar = (const float*)d_in[9];   // [2048]
    float* out = (float*)d_out;

    // Workspace layout (161 MiB total):
    //   comb  bf16 [8192,4096]  64 MiB   (u_raw|x_gate) -> (delta_raw|x_gate)
    //   uc    bf16 [8192,2048]  32 MiB
    //   bcbuf f32  [8192,32]     1 MiB
    //   delta f32  [8192,2048]  64 MiB   (-> gated y in-place)
    const size_t needed = (size_t)8192 * 4096 * 2 + (size_t)8192 * 2048 * 2
                        + (size_t)8192 * 32 * 4 + (size_t)8192 * 2048 * 4;
    if (ws_size < needed) return;  // diagnostic: clean absmax-fail, not a fault

    char* p = (char*)d_ws;
    bf16*  comb  = (bf16*)p;                          p += (size_t)8192 * 4096 * 2;
    bf16*  uc    = (bf16*)p;                          p += (size_t)8192 * 2048 * 2;
    float* bcbuf = (float*)p;                         p += (size_t)8192 * 32 * 4;
    float* delta = (float*)p;

    dim3 blk(256);

    // 1) combined = x @ in_proj_w -> comb bf16 [8192,4096]
    gemm_t<float, bf16><<<dim3(4096 / TILE_N, 8192 / TILE_M), blk, 0, stream>>>(
        x, w1, comb, 8192, 4096, 1024, 1024, 4096, 4096, nullptr, 0);

    // 2) uc = silu(conv(u_raw) + conv_b)
    conv_silu_kernel<<<(8192 * 2048) / 256, blk, 0, stream>>>(comb, cw, cb, uc);

    // 3a) delta_raw = uc @ x_proj_w[:, :2048] -> comb[:, :2048] (u_raw dead)
    gemm_t<bf16, bf16><<<dim3(2048 / TILE_N, 8192 / TILE_M), blk, 0, stream>>>(
        uc, w2, comb, 8192, 2048, 2048, 2048, 2080, 4096, nullptr, 0);

    // 3b) bc = uc @ x_proj_w[:, 2048:2080] -> bcbuf f32 [8192,32]
    gemm_t<bf16, float><<<dim3(1, 8192 / TILE_M), blk, 0, stream>>>(
        uc, w2 + 2048, bcbuf, 8192, 32, 2048, 2048, 2080, 32, nullptr, 0);

    // 4) delta = softplus(delta_raw @ dt_proj_w + dt_b) -> delta f32
    gemm_t<bf16, float><<<dim3(2048 / TILE_N, 8192 / TILE_M), blk, 0, stream>>>(
        comb, w3, delta, 8192, 2048, 2048, 4096, 2048, 2048, dtb, 1);

    // 5) selective scan + gating; in-place over delta
    scan_kernel<<<128, 64, 0, stream>>>(bcbuf, uc, comb, delta, alog, dpar);

    // 6) out = y2 @ out_proj_w -> d_out f32 [8192,1024]
    gemm_t<float, float><<<dim3(1024 / TILE_N, 8192 / TILE_M), blk, 0, stream>>>(
        delta, w4, out, 8192, 1024, 2048, 2048, 1024, 1024, nullptr, 0);
}

// Round 3
// 3432.936 us; speedup vs baseline: 1.5054x; 1.5054x over previous
//
#include <hip/hip_runtime.h>
#include <hip/hip_bf16.h>
#include <cstddef>
#include <cstdint>

// ---------------------------------------------------------------------------
// Mamba S6 layer. B=4, S=2048, D_MODEL=1024, D_STATE=16, D_CONV=3,
// D_INNER=2048, M=8192.
// Round 3: bf16 MFMA GEMMs (m97-style: 128x128 tile, BK=64, global_load_lds
// w16, XOR-swizzled LDS reads), weights transposed+cast to bf16 per call,
// lane-per-(b,d,n) scan with shfl reduce. ws footprint 160.5 MiB (<161 known
// good) via overlays + 2-chunk dt-GEMM/scan.
// ---------------------------------------------------------------------------

typedef __hip_bfloat16 bf16;
typedef unsigned int u32;
typedef short short8 __attribute__((ext_vector_type(8)));
typedef float f32x4 __attribute__((ext_vector_type(4)));

#define GLOBAL_AS __attribute__((address_space(1)))
#define LDS_AS    __attribute__((address_space(3)))

__device__ __forceinline__ void store_c(float* p, float v) { *p = v; }
__device__ __forceinline__ void store_c(bf16* p, float v)  { *p = __float2bfloat16(v); }

// C[M,N] = A[M,K](bf16) @ Bt[N,K](bf16)^T.  MODE 0: plain; 1: softplus(x+bias[n]).
// 256 threads = 4 waves (2x2 of 64x64), BM=BN=128, BK=64.
template <typename TC, int MODE>
__global__ __launch_bounds__(256) void gemm_mfma(
    const bf16* __restrict__ A, const bf16* __restrict__ Bt,
    TC* __restrict__ C, int N, int K, int lda, int ldb, int ldc,
    const float* __restrict__ bias)
{
    __shared__ short As[128 * 64];   // [row m][k], 128B rows, XOR-swizzled slots
    __shared__ short Bs[128 * 64];   // [row n][k]

    const int tid  = threadIdx.x;
    const int lane = tid & 63;
    const int w    = tid >> 6;
    const int wr   = w >> 1, wc = w & 1;
    const int m0   = blockIdx.y * 128;
    const int n0   = blockIdx.x * 128;

    const int lr = tid >> 3;   // staging row-within-round (0..31)
    const int s8 = tid & 7;    // staging k-slot (16B units)

    f32x4 acc[4][4] = {};

    const int KT = K >> 6;
    for (int kt = 0; kt < KT; ++kt) {
        const int k0 = kt << 6;
        #pragma unroll
        for (int q = 0; q < 4; ++q) {          // A tile: 4 rounds x 4KB
            int r = q * 32 + lr;
            int ks = (s8 ^ (r & 7)) * 8;       // pre-swizzled source slot
            const bf16* ga = A + (size_t)(m0 + r) * lda + k0 + ks;
            __builtin_amdgcn_global_load_lds((const GLOBAL_AS u32*)ga,
                (LDS_AS u32*)(As + q * 2048 + tid * 8), 16, 0, 0);
        }
        #pragma unroll
        for (int q = 0; q < 4; ++q) {          // B tile
            int r = q * 32 + lr;
            int ks = (s8 ^ (r & 7)) * 8;
            const bf16* gb = Bt + (size_t)(n0 + r) * ldb + k0 + ks;
            __builtin_amdgcn_global_load_lds((const GLOBAL_AS u32*)gb,
                (LDS_AS u32*)(Bs + q * 2048 + tid * 8), 16, 0, 0);
        }
        __syncthreads();                        // drains vmcnt before use
        #pragma unroll
        for (int s = 0; s < 2; ++s) {
            short8 af[4], bfr[4];
            #pragma unroll
            for (int i = 0; i < 4; ++i) {
                int r = wr * 64 + i * 16 + (lane & 15);
                int slot = ((s << 2) + (lane >> 4)) ^ (r & 7);
                af[i] = *(const short8*)&As[r * 64 + slot * 8];
            }
            #pragma unroll
            for (int j = 0; j < 4; ++j) {
                int r = wc * 64 + j * 16 + (lane & 15);
                int slot = ((s << 2) + (lane >> 4)) ^ (r & 7);
                bfr[j] = *(const short8*)&Bs[r * 64 + slot * 8];
            }
            #pragma unroll
            for (int i = 0; i < 4; ++i)
                #pragma unroll
                for (int j = 0; j < 4; ++j)
                    acc[i][j] = __builtin_amdgcn_mfma_f32_16x16x32_bf16(
                        af[i], bfr[j], acc[i][j], 0, 0, 0);
        }
        __syncthreads();                        // all reads done before restage
    }

    // epilogue: C/D layout col=lane&15, row=(lane>>4)*4+reg  [verified m89/m91]
    const int cl = lane & 15;
    const int rq = lane >> 4;
    #pragma unroll
    for (int i = 0; i < 4; ++i) {
        #pragma unroll
        for (int j = 0; j < 4; ++j) {
            int gc = n0 + wc * 64 + j * 16 + cl;
            if (gc >= N) continue;
            float bv = (MODE == 1) ? bias[gc] : 0.f;
            #pragma unroll
            for (int f = 0; f < 4; ++f) {
                int gr = m0 + wr * 64 + i * 16 + rq * 4 + f;
                float v = acc[i][j][f];
                if (MODE == 1) {
                    v += bv;
                    v = fmaxf(v, 0.f) + log1pf(__expf(-fabsf(v)));  // softplus
                }
                store_c(&C[(size_t)gr * ldc + gc], v);
            }
        }
    }
}

// wt[n][k] = (bf16) w[k][n]; rows n in [Nsrc,Npad) zero-filled.
__global__ __launch_bounds__(256) void transpose_cast(
    const float* __restrict__ src, bf16* __restrict__ dst,
    int K, int Nsrc, int Npad)
{
    __shared__ float t[32][33];
    int n0 = blockIdx.x * 32, k0 = blockIdx.y * 32;
    int lx = threadIdx.x & 31, ly = threadIdx.x >> 5;   // 32 x 8
    #pragma unroll
    for (int i = 0; i < 4; ++i) {
        int k = k0 + ly + 8 * i, n = n0 + lx;
        t[ly + 8 * i][lx] = (n < Nsrc) ? src[(size_t)k * Nsrc + n] : 0.f;
    }
    __syncthreads();
    #pragma unroll
    for (int i = 0; i < 4; ++i) {
        int n = n0 + ly + 8 * i;
        if (n < Npad) dst[(size_t)n * K + k0 + lx] = __float2bfloat16(t[lx][ly + 8 * i]);
    }
}

__global__ __launch_bounds__(256) void cast_x_kernel(
    const float* __restrict__ x, bf16* __restrict__ xb)
{
    int i = blockIdx.x * 256 + threadIdx.x;     // over float4s, 2097152 total
    float4 v = ((const float4*)x)[i];
    alignas(8) bf16 h[4] = {__float2bfloat16(v.x), __float2bfloat16(v.y),
                            __float2bfloat16(v.z), __float2bfloat16(v.w)};
    ((ushort4*)xb)[i] = *(ushort4*)h;
}

// depthwise conv w=3 SAME per-sequence + bias + SiLU
__global__ __launch_bounds__(256) void conv_silu(
    const bf16* __restrict__ ur, const float* __restrict__ cw,
    const float* __restrict__ cb, bf16* __restrict__ uc)
{
    int idx = blockIdx.x * 256 + threadIdx.x;
    int d = idx & 2047;
    int m = idx >> 11;
    int s = m & 2047;
    float w0 = cw[d * 3 + 0], w1 = cw[d * 3 + 1], w2 = cw[d * 3 + 2];
    float acc = cb[d];
    if (s > 0)    acc = fmaf(__bfloat162float(ur[(size_t)(m - 1) * 2048 + d]), w0, acc);
    acc = fmaf(__bfloat162float(ur[(size_t)m * 2048 + d]), w1, acc);
    if (s < 2047) acc = fmaf(__bfloat162float(ur[(size_t)(m + 1) * 2048 + d]), w2, acc);
    float sig = 1.f / (1.f + __expf(-acc));
    uc[(size_t)m * 2048 + d] = __float2bfloat16(acc * sig);
}

// Selective scan, lane-per-(b,d,n). 16-lane shfl reduce for y. Writes gated
// y2 bf16 in-place over uc (each element read-then-written by its own group).
__global__ __launch_bounds__(256) void scan_kernel(
    const float* __restrict__ deltaC,  // [8192,1024] f32, chunk-local
    bf16* uc,                          // [8192,2048] in: u, out: y2 (in-place)
    const bf16* __restrict__ xg,       // [8192,2048]
    const bf16* __restrict__ xdbl,     // [8192,2080]; B @2048, C @2064
    const float* __restrict__ A_log, const float* __restrict__ D_param,
    int d0)
{
    int tid = threadIdx.x;
    int n = tid & 15;
    int g = tid >> 4;                  // 16 groups per block
    int blk = blockIdx.x;              // 256 blocks
    int b = blk >> 6;
    int dl = (blk & 63) * 16 + g;      // chunk-local d (0..1023)
    int d = d0 + dl;

    float a  = -__expf(A_log[d * 16 + n]);
    float Dp = D_param[d];
    float h = 0.f;

    #pragma unroll 2
    for (int s = 0; s < 2048; ++s) {
        size_t m = (size_t)b * 2048 + s;
        float dv = deltaC[m * 1024 + dl];
        float uv = __bfloat162float(uc[m * 2048 + d]);
        float Bn = __bfloat162float(xdbl[m * 2080 + 2048 + n]);
        float Cn = __bfloat162float(xdbl[m * 2080 + 2064 + n]);
        h = __expf(dv * a) * h + (dv * Bn) * uv;
        float p = h * Cn;
        p += __shfl_xor(p, 1);
        p += __shfl_xor(p, 2);
        p += __shfl_xor(p, 4);
        p += __shfl_xor(p, 8);
        if (n == 0) {
            float xgv = __bfloat162float(xg[m * 2048 + d]);
            float sig = 1.f / (1.f + __expf(-xgv));
            float y2 = (p + uv * Dp) * (xgv * sig);
            uc[m * 2048 + d] = __float2bfloat16(y2);
        }
    }
}

extern "C" void kernel_launch(void* const* d_in, const int* in_sizes, int n_in,
                              void* d_out, int out_size, void* d_ws, size_t ws_size,
                              hipStream_t stream) {
    const float* x    = (const float*)d_in[0];
    const float* w1   = (const float*)d_in[1];   // [1024,4096]
    const float* cw   = (const float*)d_in[2];   // [2048,1,3]
    const float* cb   = (const float*)d_in[3];   // [2048]
    const float* w2   = (const float*)d_in[4];   // [2048,2080]
    const float* w3   = (const float*)d_in[5];   // [2048,2048]
    const float* dtb  = (const float*)d_in[6];   // [2048]
    const float* w4   = (const float*)d_in[7];   // [2048,1024]
    const float* alog = (const float*)d_in[8];   // [2048,16]
    const float* dpar = (const float*)d_in[9];   // [2048]
    float* out = (float*)d_out;

    // ws layout (160.5 MiB, < verified-good 161.07):
    //  [0,64 MiB) region A:
    //    phase 1: xbf[0,16) w1t[16,24) u_raw[24,56)
    //    after G1: w2t[0,8.5) w3t[8.5,16.5) w4t[16.5,20.5)
    //    after conv: deltaC f32 [24,56)
    //  [64,96)  xg bf16 [8192,2048]
    //  [96,128) uc bf16 [8192,2048] -> y2 in-place
    //  [128,160.5) xdbl bf16 [8192,2080]
    const size_t MB = 1u << 20;
    const size_t needed = 128 * MB + (size_t)8192 * 2080 * 2;
    if (ws_size < needed) return;

    char* p = (char*)d_ws;
    bf16*  xbf    = (bf16*)(p);
    bf16*  w1t    = (bf16*)(p + 16 * MB);
    bf16*  u_raw  = (bf16*)(p + 24 * MB);
    bf16*  w2t    = (bf16*)(p);                       // [2176,2048], after G1
    bf16*  w3t    = (bf16*)(p + 8912896);             // 8.5 MiB
    bf16*  w4t    = (bf16*)(p + 8912896 + 8388608);   // 16.5 MiB
    float* deltaC = (float*)(p + 24 * MB);            // [8192,1024], after conv
    bf16*  xg     = (bf16*)(p + 64 * MB);
    bf16*  uc     = (bf16*)(p + 96 * MB);
    bf16*  xdbl   = (bf16*)(p + 128 * MB);            // [8192,2080]

    // prep: cast x, transpose w1
    cast_x_kernel<<<8192, 256, 0, stream>>>(x, xbf);
    transpose_cast<<<dim3(128, 32), 256, 0, stream>>>(w1, w1t, 1024, 4096, 4096);

    // G1: u_raw = x @ W1[:, :2048]; xg = x @ W1[:, 2048:]
    gemm_mfma<bf16, 0><<<dim3(16, 64), 256, 0, stream>>>(
        xbf, w1t, u_raw, 2048, 1024, 1024, 1024, 2048, nullptr);
    gemm_mfma<bf16, 0><<<dim3(16, 64), 256, 0, stream>>>(
        xbf, w1t + (size_t)2048 * 1024, xg, 2048, 1024, 1024, 1024, 2048, nullptr);

    // transposes for later GEMMs (overlay xbf/w1t, now dead)
    transpose_cast<<<dim3(68, 64), 256, 0, stream>>>(w2, w2t, 2048, 2080, 2176);
    transpose_cast<<<dim3(64, 64), 256, 0, stream>>>(w3, w3t, 2048, 2048, 2048);
    transpose_cast<<<dim3(32, 64), 256, 0, stream>>>(w4, w4t, 2048, 1024, 1024);

    // conv + SiLU
    conv_silu<<<(8192 * 2048) / 256, 256, 0, stream>>>(u_raw, cw, cb, uc);

    // G3: xdbl = uc @ x_proj_w  (N=2080 incl. B,C; padded Bt rows are zero)
    gemm_mfma<bf16, 0><<<dim3(17, 64), 256, 0, stream>>>(
        uc, w2t, xdbl, 2080, 2048, 2048, 2048, 2080, nullptr);

    // G4 chunk 1 + scan chunk 1 (d 0..1023)
    gemm_mfma<float, 1><<<dim3(8, 64), 256, 0, stream>>>(
        xdbl, w3t, deltaC, 1024, 2048, 2080, 2048, 1024, dtb);
    scan_kernel<<<256, 256, 0, stream>>>(deltaC, uc, xg, xdbl, alog, dpar, 0);

    // G4 chunk 2 + scan chunk 2 (d 1024..2047)
    gemm_mfma<float, 1><<<dim3(8, 64), 256, 0, stream>>>(
        xdbl, w3t + (size_t)1024 * 2048, deltaC, 1024, 2048, 2080, 2048, 1024,
        dtb + 1024);
    scan_kernel<<<256, 256, 0, stream>>>(deltaC, uc, xg, xdbl, alog, dpar, 1024);

    // G6: out = y2 @ out_proj_w
    gemm_mfma<float, 0><<<dim3(8, 64), 256, 0, stream>>>(
        uc, w4t, out, 1024, 2048, 2048, 2048, 1024, nullptr);
}

// Round 4
// 747.729 us; speedup vs baseline: 6.9115x; 4.5912x over previous
//
#include <hip/hip_runtime.h>
#include <hip/hip_bf16.h>
#include <cstddef>
#include <cstdint>

// ---------------------------------------------------------------------------
// Mamba S6 layer. B=4, S=2048, D_MODEL=1024, D_STATE=16, D_CONV=3,
// D_INNER=2048, M=8192.
// Round 4: chunk-parallel selective scan (3-phase: partial / combine / final,
// NC=16 chunks of L=128) replacing the 2048-step serial scan; vectorized conv.
// GEMMs unchanged from round 3 (proven). ws footprint 152.5 MiB.
// ---------------------------------------------------------------------------

typedef __hip_bfloat16 bf16;
typedef unsigned int u32;
typedef short short8 __attribute__((ext_vector_type(8)));
typedef float f32x4 __attribute__((ext_vector_type(4)));

#define GLOBAL_AS __attribute__((address_space(1)))
#define LDS_AS    __attribute__((address_space(3)))

__device__ __forceinline__ float bf2f(short s) {
    union { float f; u32 u; } x; x.u = ((u32)(unsigned short)s) << 16; return x.f;
}
__device__ __forceinline__ void store_c(float* p, float v) { *p = v; }
__device__ __forceinline__ void store_c(bf16* p, float v)  { *p = __float2bfloat16(v); }

// C[M,N] = A[M,K](bf16) @ Bt[N,K](bf16)^T.  MODE 0: plain; 1: softplus(x+bias[n]).
// 256 threads = 4 waves (2x2 of 64x64), BM=BN=128, BK=64.
template <typename TC, int MODE>
__global__ __launch_bounds__(256) void gemm_mfma(
    const bf16* __restrict__ A, const bf16* __restrict__ Bt,
    TC* __restrict__ C, int N, int K, int lda, int ldb, int ldc,
    const float* __restrict__ bias)
{
    __shared__ short As[128 * 64];
    __shared__ short Bs[128 * 64];

    const int tid  = threadIdx.x;
    const int lane = tid & 63;
    const int w    = tid >> 6;
    const int wr   = w >> 1, wc = w & 1;
    const int m0   = blockIdx.y * 128;
    const int n0   = blockIdx.x * 128;

    const int lr = tid >> 3;
    const int s8 = tid & 7;

    f32x4 acc[4][4] = {};

    const int KT = K >> 6;
    for (int kt = 0; kt < KT; ++kt) {
        const int k0 = kt << 6;
        #pragma unroll
        for (int q = 0; q < 4; ++q) {
            int r = q * 32 + lr;
            int ks = (s8 ^ (r & 7)) * 8;
            const bf16* ga = A + (size_t)(m0 + r) * lda + k0 + ks;
            __builtin_amdgcn_global_load_lds((const GLOBAL_AS u32*)ga,
                (LDS_AS u32*)(As + q * 2048 + tid * 8), 16, 0, 0);
        }
        #pragma unroll
        for (int q = 0; q < 4; ++q) {
            int r = q * 32 + lr;
            int ks = (s8 ^ (r & 7)) * 8;
            const bf16* gb = Bt + (size_t)(n0 + r) * ldb + k0 + ks;
            __builtin_amdgcn_global_load_lds((const GLOBAL_AS u32*)gb,
                (LDS_AS u32*)(Bs + q * 2048 + tid * 8), 16, 0, 0);
        }
        __syncthreads();
        #pragma unroll
        for (int s = 0; s < 2; ++s) {
            short8 af[4], bfr[4];
            #pragma unroll
            for (int i = 0; i < 4; ++i) {
                int r = wr * 64 + i * 16 + (lane & 15);
                int slot = ((s << 2) + (lane >> 4)) ^ (r & 7);
                af[i] = *(const short8*)&As[r * 64 + slot * 8];
            }
            #pragma unroll
            for (int j = 0; j < 4; ++j) {
                int r = wc * 64 + j * 16 + (lane & 15);
                int slot = ((s << 2) + (lane >> 4)) ^ (r & 7);
                bfr[j] = *(const short8*)&Bs[r * 64 + slot * 8];
            }
            #pragma unroll
            for (int i = 0; i < 4; ++i)
                #pragma unroll
                for (int j = 0; j < 4; ++j)
                    acc[i][j] = __builtin_amdgcn_mfma_f32_16x16x32_bf16(
                        af[i], bfr[j], acc[i][j], 0, 0, 0);
        }
        __syncthreads();
    }

    const int cl = lane & 15;
    const int rq = lane >> 4;
    #pragma unroll
    for (int i = 0; i < 4; ++i) {
        #pragma unroll
        for (int j = 0; j < 4; ++j) {
            int gc = n0 + wc * 64 + j * 16 + cl;
            if (gc >= N) continue;
            float bv = (MODE == 1) ? bias[gc] : 0.f;
            #pragma unroll
            for (int f = 0; f < 4; ++f) {
                int gr = m0 + wr * 64 + i * 16 + rq * 4 + f;
                float v = acc[i][j][f];
                if (MODE == 1) {
                    v += bv;
                    v = fmaxf(v, 0.f) + log1pf(__expf(-fabsf(v)));
                }
                store_c(&C[(size_t)gr * ldc + gc], v);
            }
        }
    }
}

// wt[n][k] = (bf16) w[k][n]; rows n in [Nsrc,Npad) zero-filled.
__global__ __launch_bounds__(256) void transpose_cast(
    const float* __restrict__ src, bf16* __restrict__ dst,
    int K, int Nsrc, int Npad)
{
    __shared__ float t[32][33];
    int n0 = blockIdx.x * 32, k0 = blockIdx.y * 32;
    int lx = threadIdx.x & 31, ly = threadIdx.x >> 5;
    #pragma unroll
    for (int i = 0; i < 4; ++i) {
        int k = k0 + ly + 8 * i, n = n0 + lx;
        t[ly + 8 * i][lx] = (n < Nsrc) ? src[(size_t)k * Nsrc + n] : 0.f;
    }
    __syncthreads();
    #pragma unroll
    for (int i = 0; i < 4; ++i) {
        int n = n0 + ly + 8 * i;
        if (n < Npad) dst[(size_t)n * K + k0 + lx] = __float2bfloat16(t[lx][ly + 8 * i]);
    }
}

__global__ __launch_bounds__(256) void cast_x_kernel(
    const float* __restrict__ x, bf16* __restrict__ xb)
{
    int i = blockIdx.x * 256 + threadIdx.x;
    float4 v = ((const float4*)x)[i];
    alignas(8) bf16 h[4] = {__float2bfloat16(v.x), __float2bfloat16(v.y),
                            __float2bfloat16(v.z), __float2bfloat16(v.w)};
    ((ushort4*)xb)[i] = *(ushort4*)h;
}

// depthwise conv w=3 SAME per-sequence + bias + SiLU; 8 channels/thread.
__global__ __launch_bounds__(256) void conv_silu(
    const bf16* __restrict__ ur, const float* __restrict__ cw,
    const float* __restrict__ cb, bf16* __restrict__ uc)
{
    int idx = blockIdx.x * 256 + threadIdx.x;   // 2097152 = 8192*256
    int d8 = idx & 255;
    int m  = idx >> 8;
    int s  = m & 2047;
    int d0 = d8 << 3;

    short8 z = {0, 0, 0, 0, 0, 0, 0, 0};
    short8 u0 = *(const short8*)&ur[(size_t)m * 2048 + d0];
    short8 um = (s > 0)    ? *(const short8*)&ur[(size_t)(m - 1) * 2048 + d0] : z;
    short8 up = (s < 2047) ? *(const short8*)&ur[(size_t)(m + 1) * 2048 + d0] : z;

    float wv[24];
    #pragma unroll
    for (int q = 0; q < 6; ++q) *(float4*)&wv[q * 4] = ((const float4*)(cw + d0 * 3))[q];
    float bv[8];
    *(float4*)&bv[0] = ((const float4*)(cb + d0))[0];
    *(float4*)&bv[4] = ((const float4*)(cb + d0))[1];

    alignas(16) bf16 o[8];
    #pragma unroll
    for (int i = 0; i < 8; ++i) {
        float acc = bv[i] + wv[i * 3] * bf2f(um[i]) + wv[i * 3 + 1] * bf2f(u0[i])
                  + wv[i * 3 + 2] * bf2f(up[i]);
        float sig = 1.f / (1.f + __expf(-acc));
        o[i] = __float2bfloat16(acc * sig);
    }
    *(short8*)&uc[(size_t)m * 2048 + d0] = *(short8*)o;
}

// ---- chunk-parallel selective scan: NC=16 chunks of L=128 ------------------
// summaries layout: [b][c][n][dl], idx = (((b*16+c)*16+n)<<10) + dl

// Phase A: per (b,dl,c): local scan with h_in=0; store final hl and prod(alpha).
__global__ __launch_bounds__(256) void scan_partial(
    const float* __restrict__ deltaC,  // [8192,1024]
    const bf16* __restrict__ uc,       // [8192,2048]
    const bf16* __restrict__ xdbl,     // [8192,2080]; B @2048, C @2064
    const float* __restrict__ A_log,
    float* __restrict__ hout, float* __restrict__ aprod, int d0)
{
    int dl = blockIdx.x * 256 + threadIdx.x;   // grid.x=4
    int c  = blockIdx.y;
    int b  = blockIdx.z;
    int d  = d0 + dl;

    float a[16];
    #pragma unroll
    for (int n = 0; n < 16; ++n) a[n] = -__expf(A_log[d * 16 + n]);
    float hl[16] = {};
    float P[16];
    #pragma unroll
    for (int n = 0; n < 16; ++n) P[n] = 1.f;

    size_t mbase = (size_t)b * 2048 + c * 128;
    for (int s = 0; s < 128; ++s) {
        size_t m = mbase + s;
        float dv = deltaC[m * 1024 + dl];
        float uv = bf2f(*(const short*)&uc[m * 2048 + d]);
        const short8* bp = (const short8*)&xdbl[m * 2080 + 2048];
        short8 B0 = bp[0], B1 = bp[1];
        float du = dv * uv;
        #pragma unroll
        for (int n = 0; n < 16; ++n) {
            float al = __expf(dv * a[n]);
            float Bn = bf2f(n < 8 ? B0[n] : B1[n - 8]);
            hl[n] = al * hl[n] + du * Bn;
            P[n] *= al;
        }
    }
    #pragma unroll
    for (int n = 0; n < 16; ++n) {
        int idx = (((b * 16 + c) * 16 + n) << 10) + dl;
        hout[idx]  = hl[n];
        aprod[idx] = P[n];
    }
}

// Phase B: per (b,dl,n): scan the 16 chunk summaries; hout becomes h_in (in-place).
__global__ __launch_bounds__(256) void scan_combine(
    float* hout, const float* __restrict__ aprod)
{
    int dl = blockIdx.x * 256 + threadIdx.x;
    int n  = blockIdx.y;
    int b  = blockIdx.z;
    float H = 0.f;
    for (int c = 0; c < 16; ++c) {
        int idx = (((b * 16 + c) * 16 + n) << 10) + dl;
        float he = hout[idx];
        float Pp = aprod[idx];
        hout[idx] = H;            // h at chunk start
        H = Pp * H + he;
    }
}

// Phase C: recompute with corrected h_start; gate; y2 bf16 in-place over xg.
__global__ __launch_bounds__(256) void scan_final(
    const float* __restrict__ deltaC,
    const bf16* __restrict__ uc,
    const bf16* __restrict__ xdbl,
    const float* __restrict__ hin,     // = hout after combine
    const float* __restrict__ A_log, const float* __restrict__ D_param,
    bf16* ygate,                       // [8192,2048]: in xg, out y2 (in-place)
    int d0)
{
    int dl = blockIdx.x * 256 + threadIdx.x;
    int c  = blockIdx.y;
    int b  = blockIdx.z;
    int d  = d0 + dl;

    float a[16], H[16];
    #pragma unroll
    for (int n = 0; n < 16; ++n) {
        a[n] = -__expf(A_log[d * 16 + n]);
        H[n] = hin[(((b * 16 + c) * 16 + n) << 10) + dl];
    }
    float Dp = D_param[d];
    float hl[16] = {};
    float P[16];
    #pragma unroll
    for (int n = 0; n < 16; ++n) P[n] = 1.f;

    size_t mbase = (size_t)b * 2048 + c * 128;
    // prefetch xg for s=0 (loads stay ahead of the in-place stores)
    float xg_cur = bf2f(*(const short*)&ygate[mbase * 2048 + d]);

    for (int s = 0; s < 128; ++s) {
        size_t m = mbase + s;
        float dv = deltaC[m * 1024 + dl];
        float uv = bf2f(*(const short*)&uc[m * 2048 + d]);
        const short8* bp = (const short8*)&xdbl[m * 2080 + 2048];
        short8 B0 = bp[0], B1 = bp[1], C0 = bp[2], C1 = bp[3];
        float du = dv * uv;
        float y = 0.f;
        #pragma unroll
        for (int n = 0; n < 16; ++n) {
            float al = __expf(dv * a[n]);
            float Bn = bf2f(n < 8 ? B0[n] : B1[n - 8]);
            float Cn = bf2f(n < 8 ? C0[n] : C1[n - 8]);
            hl[n] = al * hl[n] + du * Bn;
            P[n] *= al;
            float ht = fmaf(P[n], H[n], hl[n]);
            y = fmaf(ht, Cn, y);
        }
        float xgv = xg_cur;
        if (s < 127) xg_cur = bf2f(*(const short*)&ygate[(m + 1) * 2048 + d]);
        float sig = 1.f / (1.f + __expf(-xgv));
        float y2 = (y + uv * Dp) * (xgv * sig);
        ygate[m * 2048 + d] = __float2bfloat16(y2);
    }
}

extern "C" void kernel_launch(void* const* d_in, const int* in_sizes, int n_in,
                              void* d_out, int out_size, void* d_ws, size_t ws_size,
                              hipStream_t stream) {
    const float* x    = (const float*)d_in[0];
    const float* w1   = (const float*)d_in[1];   // [1024,4096]
    const float* cw   = (const float*)d_in[2];   // [2048,1,3]
    const float* cb   = (const float*)d_in[3];   // [2048]
    const float* w2   = (const float*)d_in[4];   // [2048,2080]
    const float* w3   = (const float*)d_in[5];   // [2048,2048]
    const float* dtb  = (const float*)d_in[6];   // [2048]
    const float* w4   = (const float*)d_in[7];   // [2048,1024]
    const float* alog = (const float*)d_in[8];   // [2048,16]
    const float* dpar = (const float*)d_in[9];   // [2048]
    float* out = (float*)d_out;

    // ws layout (152.5 MiB):
    //  [0,24):    phase1 xbf(16)+w1t(8); after G1: w2t(8.5)+w3t(8)+w4t(4)
    //             after G3: summ_h(4)+summ_a(4) overlay w2t's [0,8)
    //  [24,56):   u_raw bf16 -> (after conv) deltaC f32 [8192,1024]
    //  [56,88):   xg bf16 -> y2 in-place (scan C)
    //  [88,120):  uc bf16
    //  [120,152.5): xdbl bf16 [8192,2080]
    const size_t MB = 1u << 20;
    const size_t needed = 120 * MB + (size_t)8192 * 2080 * 2;
    if (ws_size < needed) return;

    char* p = (char*)d_ws;
    bf16*  xbf    = (bf16*)(p);
    bf16*  w1t    = (bf16*)(p + 16 * MB);
    bf16*  u_raw  = (bf16*)(p + 24 * MB);
    bf16*  w2t    = (bf16*)(p);                       // [2176,2048]
    bf16*  w3t    = (bf16*)(p + 8912896);             // 8.5 MiB
    bf16*  w4t    = (bf16*)(p + 8912896 + 8388608);   // 16.5 MiB
    float* summ_h = (float*)(p);                      // 4 MiB, after G3
    float* summ_a = (float*)(p + 4 * MB);             // 4 MiB
    float* deltaC = (float*)(p + 24 * MB);            // [8192,1024] f32
    bf16*  xg     = (bf16*)(p + 56 * MB);
    bf16*  uc     = (bf16*)(p + 88 * MB);
    bf16*  xdbl   = (bf16*)(p + 120 * MB);            // [8192,2080]

    cast_x_kernel<<<8192, 256, 0, stream>>>(x, xbf);
    transpose_cast<<<dim3(128, 32), 256, 0, stream>>>(w1, w1t, 1024, 4096, 4096);

    // G1: u_raw = x @ W1[:, :2048]; xg = x @ W1[:, 2048:]
    gemm_mfma<bf16, 0><<<dim3(16, 64), 256, 0, stream>>>(
        xbf, w1t, u_raw, 2048, 1024, 1024, 1024, 2048, nullptr);
    gemm_mfma<bf16, 0><<<dim3(16, 64), 256, 0, stream>>>(
        xbf, w1t + (size_t)2048 * 1024, xg, 2048, 1024, 1024, 1024, 2048, nullptr);

    transpose_cast<<<dim3(68, 64), 256, 0, stream>>>(w2, w2t, 2048, 2080, 2176);
    transpose_cast<<<dim3(64, 64), 256, 0, stream>>>(w3, w3t, 2048, 2048, 2048);
    transpose_cast<<<dim3(32, 64), 256, 0, stream>>>(w4, w4t, 2048, 1024, 1024);

    conv_silu<<<8192, 256, 0, stream>>>(u_raw, cw, cb, uc);

    // G3: xdbl = uc @ x_proj_w  (N=2080; padded Bt rows are zero)
    gemm_mfma<bf16, 0><<<dim3(17, 64), 256, 0, stream>>>(
        uc, w2t, xdbl, 2080, 2048, 2048, 2048, 2080, nullptr);

    for (int chunk = 0; chunk < 2; ++chunk) {
        int d0 = chunk * 1024;
        gemm_mfma<float, 1><<<dim3(8, 64), 256, 0, stream>>>(
            xdbl, w3t + (size_t)d0 * 2048, deltaC, 1024, 2048, 2080, 2048, 1024,
            dtb + d0);
        scan_partial<<<dim3(4, 16, 4), 256, 0, stream>>>(
            deltaC, uc, xdbl, alog, summ_h, summ_a, d0);
        scan_combine<<<dim3(4, 16, 4), 256, 0, stream>>>(summ_h, summ_a);
        scan_final<<<dim3(4, 16, 4), 256, 0, stream>>>(
            deltaC, uc, xdbl, summ_h, alog, dpar, xg, d0);
    }

    // G6: out = y2 @ out_proj_w
    gemm_mfma<float, 0><<<dim3(8, 64), 256, 0, stream>>>(
        xg, w4t, out, 1024, 2048, 2048, 2048, 1024, nullptr);
}